// Round 9
// baseline (577.777 us; speedup 1.0000x reference)
//
#include <hip/hip_runtime.h>
#include <cmath>

#define BATCH 256
#define SEQL  128
#define NBD   6
#define FPC   200
#define BL    (BATCH*SEQL)   /* 32768 */
#define NEGV  -9e8f

typedef __attribute__((ext_vector_type(8))) short short8;
typedef __attribute__((ext_vector_type(4))) float f32x4;

__device__ __forceinline__ float wave_sum(float v) {
#pragma unroll
    for (int o = 32; o > 0; o >>= 1) v += __shfl_xor(v, o);
    return v;
}
__device__ __forceinline__ float wave_max(float v) {
#pragma unroll
    for (int o = 32; o > 0; o >>= 1) v = fmaxf(v, __shfl_xor(v, o));
    return v;
}
__device__ __forceinline__ float leakyf(float x){ return x > 0.f ? x : 0.01f*x; }
__device__ __forceinline__ unsigned short f2bf(float f){
    unsigned int x = __float_as_uint(f);
    return (unsigned short)((x + 0x7fffu + ((x >> 16) & 1u)) >> 16);
}
__device__ __forceinline__ float bf2f(unsigned short u){
    return __uint_as_float(((unsigned int)u) << 16);
}
__device__ __forceinline__ float sigm(float x){ return 1.f/(1.f+expf(-x)); }

// ---------------------------------------------------------------------------
// fp32 tiled GEMM: C = act(A@W^T [+ bias]), f32 and/or bf16 outputs.
// ---------------------------------------------------------------------------
template<int ACT, bool BI, bool WF32, bool WBF>
__global__ __launch_bounds__(256)
void gemm_bt(const float* __restrict__ A, int lda,
             const float* __restrict__ W, int ldw,
             const float* __restrict__ bias,
             float* __restrict__ C, unsigned short* __restrict__ Ch, int ldc,
             int M, int N, int K)
{
    __shared__ float As[16][68];
    __shared__ float Ws[16][68];
    const int tid = threadIdx.x;
    const int bm = blockIdx.x * 64;
    const int bn = blockIdx.y * 64;
    const int tx = tid & 15;
    const int ty = tid >> 4;
    const int lr = tid >> 2;
    const int lk = (tid & 3) << 2;
    float acc[4][4] = {};

    for (int k0 = 0; k0 < K; k0 += 16) {
        float a0=0.f,a1=0.f,a2=0.f,a3=0.f, w0=0.f,w1=0.f,w2=0.f,w3=0.f;
        {
            const int rem = K - (k0 + lk);
            const int m = bm + lr;
            if (m < M) {
                const float* p = A + (size_t)m*lda + k0 + lk;
                if (rem > 0) a0 = p[0];
                if (rem > 1) a1 = p[1];
                if (rem > 2) a2 = p[2];
                if (rem > 3) a3 = p[3];
            }
            const int n = bn + lr;
            if (n < N) {
                const float* p = W + (size_t)n*ldw + k0 + lk;
                if (rem > 0) w0 = p[0];
                if (rem > 1) w1 = p[1];
                if (rem > 2) w2 = p[2];
                if (rem > 3) w3 = p[3];
            }
        }
        __syncthreads();
        As[lk+0][lr]=a0; As[lk+1][lr]=a1; As[lk+2][lr]=a2; As[lk+3][lr]=a3;
        Ws[lk+0][lr]=w0; Ws[lk+1][lr]=w1; Ws[lk+2][lr]=w2; Ws[lk+3][lr]=w3;
        __syncthreads();
#pragma unroll
        for (int kk = 0; kk < 16; kk++) {
            const float4 av4 = *reinterpret_cast<const float4*>(&As[kk][ty<<2]);
            const float4 wv4 = *reinterpret_cast<const float4*>(&Ws[kk][tx<<2]);
            const float av[4] = {av4.x, av4.y, av4.z, av4.w};
            const float wv[4] = {wv4.x, wv4.y, wv4.z, wv4.w};
#pragma unroll
            for (int i=0;i<4;i++)
#pragma unroll
                for (int j=0;j<4;j++)
                    acc[i][j] = fmaf(av[i], wv[j], acc[i][j]);
        }
    }
#pragma unroll
    for (int i=0;i<4;i++){
        const int m = bm + (ty<<2) + i;
        if (m >= M) continue;
#pragma unroll
        for (int j=0;j<4;j++){
            const int n = bn + (tx<<2) + j;
            if (n >= N) continue;
            float v = acc[i][j];
            if (BI) v += bias[n];
            if (ACT==1) v = leakyf(v);
            else if (ACT==2) v = v > 0.f ? v : (expf(v)-1.f);
            if (WF32) C[(size_t)m*ldc + n] = v;
            if (WBF)  Ch[(size_t)m*ldc + n] = f2bf(v);
        }
    }
}

// ---------------------------------------------------------------------------
// bf16 MFMA GEMM (attend layer): Ch = elu(A@W^T + bias*rowscale), bf16 out.
// Tile 64x128, 4 waves (2x2). M % 64 == 0, K % 8 == 0.
// ---------------------------------------------------------------------------
template<int ACT, bool RS>
__global__ __launch_bounds__(256)
void gemm_mfma(const unsigned short* __restrict__ A, int lda,
               const unsigned short* __restrict__ W, int ldw,
               const float* __restrict__ bias,
               const float* __restrict__ rowscale,
               unsigned short* __restrict__ Ch, int ldc,
               int M, int N, int K)
{
    __shared__ unsigned short As[64*40];
    __shared__ unsigned short Ws[128*40];
    const int tid = threadIdx.x;
    const int bm = blockIdx.x * 64;
    const int bn = blockIdx.y * 128;
    const int wid = tid >> 6;
    const int lane = tid & 63;
    const int wm = wid >> 1;
    const int wn = wid & 1;
    const int l15 = lane & 15;
    const int kq  = lane >> 4;
    const int koff = kq * 8;

    f32x4 acc[2][4];
#pragma unroll
    for (int i=0;i<2;i++)
#pragma unroll
        for (int j=0;j<4;j++) acc[i][j] = (f32x4){0.f,0.f,0.f,0.f};

    const int sr = tid >> 2;
    const int sk = (tid & 3) * 8;

    for (int k0 = 0; k0 < K; k0 += 32) {
        uint4 av = {0,0,0,0}, wv0 = {0,0,0,0}, wv1 = {0,0,0,0};
        const int kc = k0 + sk;
        if (kc + 8 <= K) {
            av = *reinterpret_cast<const uint4*>(A + (size_t)(bm+sr)*lda + kc);
            const int n0 = bn + sr;
            if (n0 < N) wv0 = *reinterpret_cast<const uint4*>(W + (size_t)n0*ldw + kc);
            const int n1 = bn + sr + 64;
            if (n1 < N) wv1 = *reinterpret_cast<const uint4*>(W + (size_t)n1*ldw + kc);
        }
        __syncthreads();
        *reinterpret_cast<uint4*>(&As[sr*40 + sk]) = av;
        *reinterpret_cast<uint4*>(&Ws[sr*40 + sk]) = wv0;
        *reinterpret_cast<uint4*>(&Ws[(sr+64)*40 + sk]) = wv1;
        __syncthreads();
        short8 af[2], bfr[4];
#pragma unroll
        for (int i=0;i<2;i++)
            af[i] = *reinterpret_cast<const short8*>(&As[(wm*32 + i*16 + l15)*40 + koff]);
#pragma unroll
        for (int j=0;j<4;j++)
            bfr[j] = *reinterpret_cast<const short8*>(&Ws[(wn*64 + j*16 + l15)*40 + koff]);
#pragma unroll
        for (int i=0;i<2;i++)
#pragma unroll
            for (int j=0;j<4;j++)
                acc[i][j] = __builtin_amdgcn_mfma_f32_16x16x32_bf16(af[i], bfr[j], acc[i][j], 0, 0, 0);
    }
#pragma unroll
    for (int i=0;i<2;i++){
        const int mrow0 = bm + wm*32 + i*16 + kq*4;
#pragma unroll
        for (int j=0;j<4;j++){
            const int n = bn + wn*64 + j*16 + l15;
            if (n >= N) continue;
            const float bb = bias[n];
#pragma unroll
            for (int r=0;r<4;r++){
                const int m = mrow0 + r;
                float v = acc[i][j][r] + bb * (RS ? rowscale[m] : 1.f);
                if (ACT==1) v = leakyf(v);
                else if (ACT==2) v = v>0.f ? v : (expf(v)-1.f);
                Ch[(size_t)m*ldc + n] = f2bf(v);
            }
        }
    }
}

// ---------------------------------------------------------------------------
// Fused GRU v3b. Grid (1024), 256 thr (4 waves). Per block: 32 rows, all cols.
// LDS stride 232 shorts (29 x 16B quads, odd -> conflict-free ds_read_b128).
// Tail columns [200,232) ZERO-FILLED (read by last K-iter fragments).
// Panels: cb = p*4 + w, cb in [0,13).
// ---------------------------------------------------------------------------
__global__ __launch_bounds__(256, 4)
void gru_fused(const unsigned short* __restrict__ ctxh,
               const unsigned short* __restrict__ hhIn,
               const unsigned short* __restrict__ wpIh,
               const unsigned short* __restrict__ wpHh,
               const float* __restrict__ bpIh,
               const float* __restrict__ bpHh,
               unsigned short* __restrict__ hhOut,
               float* __restrict__ hOutF32)
{
    __shared__ unsigned short A1s[32*232];
    __shared__ unsigned short A2s[32*232];
    const int tid = threadIdx.x;
    const int bm = blockIdx.x * 32;
    const int w = tid >> 6, lane = tid & 63;
    const int l15 = lane & 15, kq = lane >> 4;
    const int koff = kq * 8;

    for (int u = tid; u < 32*29; u += 256) {
        const int r = u / 29, c = (u % 29) * 8;
        uint4 v1 = {0,0,0,0}, v2 = {0,0,0,0};
        if (c + 8 <= FPC) {
            v1 = *reinterpret_cast<const uint4*>(&ctxh[(size_t)(bm+r)*FPC + c]);
            v2 = *reinterpret_cast<const uint4*>(&hhIn[(size_t)(bm+r)*FPC + c]);
        }
        *reinterpret_cast<uint4*>(&A1s[r*232 + c]) = v1;
        *reinterpret_cast<uint4*>(&A2s[r*232 + c]) = v2;
    }
    __syncthreads();

    for (int p = 0; p < 4; ++p) {
        const int cb = p*4 + w;
        if (cb > 12) break;                 // divergent exit OK: no barriers below
        f32x4 accA[2][3], accB[2][3];
#pragma unroll
        for (int i=0;i<2;i++)
#pragma unroll
            for (int j=0;j<3;j++){
                accA[i][j] = (f32x4){0.f,0.f,0.f,0.f};
                accB[i][j] = (f32x4){0.f,0.f,0.f,0.f};
            }
        for (int k0 = 0; k0 < FPC; k0 += 32) {
            const int kc = k0 + koff;
            short8 a1f[2], a2f[2], w1f[3], w2f[3];
#pragma unroll
            for (int i=0;i<2;i++){
                a1f[i] = *reinterpret_cast<const short8*>(&A1s[(i*16 + l15)*232 + kc]);
                a2f[i] = *reinterpret_cast<const short8*>(&A2s[(i*16 + l15)*232 + kc]);
            }
            const bool kval = (kc + 8 <= FPC);
#pragma unroll
            for (int j=0;j<3;j++){
                const int wr = cb*48 + j*16 + l15;
                w1f[j] = kval ? *reinterpret_cast<const short8*>(&wpIh[(size_t)wr*FPC + kc])
                              : (short8){0,0,0,0,0,0,0,0};
                w2f[j] = kval ? *reinterpret_cast<const short8*>(&wpHh[(size_t)wr*FPC + kc])
                              : (short8){0,0,0,0,0,0,0,0};
            }
#pragma unroll
            for (int i=0;i<2;i++)
#pragma unroll
                for (int j=0;j<3;j++){
                    accA[i][j] = __builtin_amdgcn_mfma_f32_16x16x32_bf16(a1f[i], w1f[j], accA[i][j], 0, 0, 0);
                    accB[i][j] = __builtin_amdgcn_mfma_f32_16x16x32_bf16(a2f[i], w2f[j], accB[i][j], 0, 0, 0);
                }
        }
        const int ch = cb*16 + l15;
        if (ch < FPC) {
            const int p0 = cb*48 + l15;
            const float bi0 = bpIh[p0], bi1 = bpIh[p0+16], bi2 = bpIh[p0+32];
            const float bh0 = bpHh[p0], bh1 = bpHh[p0+16], bh2 = bpHh[p0+32];
#pragma unroll
            for (int i=0;i<2;i++){
#pragma unroll
                for (int r=0;r<4;r++){
                    const int ml = i*16 + kq*4 + r;
                    const int m = bm + ml;
                    const float rr = sigm(accA[i][0][r] + bi0 + accB[i][0][r] + bh0);
                    const float zz = sigm(accA[i][1][r] + bi1 + accB[i][1][r] + bh1);
                    const float nn = tanhf(accA[i][2][r] + bi2 + rr*(accB[i][2][r] + bh2));
                    const float hp = bf2f(A2s[ml*232 + ch]);
                    const float o  = (1.f - zz)*nn + zz*hp;
                    if (hhOut)   hhOut[(size_t)m*FPC + ch] = f2bf(o);
                    if (hOutF32) hOutF32[(size_t)m*FPC + ch] = o;
                }
            }
        }
    }
}

// ---------------------------------------------------------------------------
__global__ __launch_bounds__(256)
void conv_perm(const float* __restrict__ wih, const float* __restrict__ whh,
               const float* __restrict__ bih, const float* __restrict__ bhh,
               unsigned short* __restrict__ wpIh, unsigned short* __restrict__ wpHh,
               float* __restrict__ bpIh, float* __restrict__ bpHh)
{
    const int idx = blockIdx.x*256 + threadIdx.x;
    if (idx >= 3*768*FPC) return;
    const int d = idx / (768*FPC);
    const int rem = idx - d*768*FPC;
    const int pn = rem / FPC;
    const int k = rem - pn*FPC;
    const int cb = pn / 48, w48 = pn % 48;
    const int g = w48 >> 4, ci = w48 & 15;
    const int ch = cb*16 + ci;
    unsigned short vi = 0, vh = 0;
    if (ch < FPC) {
        vi = f2bf(wih[(size_t)d*3*FPC*FPC + (size_t)(g*FPC+ch)*FPC + k]);
        vh = f2bf(whh[(size_t)d*3*FPC*FPC + (size_t)(g*FPC+ch)*FPC + k]);
    }
    wpIh[idx] = vi; wpHh[idx] = vh;
    if (k == 0) {
        bpIh[d*768+pn] = (ch < FPC) ? bih[d*3*FPC + g*FPC + ch] : 0.f;
        bpHh[d*768+pn] = (ch < FPC) ? bhh[d*3*FPC + g*FPC + ch] : 0.f;
    }
}

__global__ __launch_bounds__(256)
void conv_bf(const float* __restrict__ src, unsigned short* __restrict__ dst, int n)
{
    const int i = blockIdx.x*blockDim.x + threadIdx.x;
    if (i < n) dst[i] = f2bf(src[i]);
}

// ---------------------------------------------------------------------------
__global__ __launch_bounds__(256)
void mol_prep(const float* __restrict__ attw, const float* __restrict__ wih,
              const float* __restrict__ whh,
              float* __restrict__ attwT, float* __restrict__ wihT,
              float* __restrict__ whhT)
{
    const int idx = blockIdx.x*256 + threadIdx.x;
    if (idx < 40000) {
        const int o = idx / FPC, k = idx % FPC;
        attwT[k*FPC + o] = attw[o*FPC + k];
    } else if (idx < 160000) {
        const int i = idx - 40000, o = i / FPC, k = i % FPC;
        wihT[k*600 + o] = wih[(size_t)o*FPC + k];
    } else if (idx < 280000) {
        const int i = idx - 160000, o = i / FPC, k = i % FPC;
        whhT[k*600 + o] = whh[(size_t)o*FPC + k];
    }
}

// ---------------------------------------------------------------------------
// Per-atom neighbor attention, bf16 activations. 4 atoms per 256-thr block.
// ---------------------------------------------------------------------------
template<bool D0, bool RELU>
__global__ __launch_bounds__(256)
void attn_radius(const unsigned short* __restrict__ cur,
                 const unsigned short* __restrict__ nbh,
                 const unsigned short* __restrict__ nb1,
                 const unsigned short* __restrict__ nb2,
                 const int* __restrict__ adl, const int* __restrict__ bdl,
                 const float* __restrict__ aw_, const float* __restrict__ ab_,
                 unsigned short* __restrict__ wnbh, float* __restrict__ s_aw)
{
    const int atom = blockIdx.x * 4 + (threadIdx.x >> 6);
    const int lane = threadIdx.x & 63;
    const unsigned short* crow = cur + (size_t)atom*FPC;
    int   cc[4]; bool val[4];
    float a2[4];
    float s1p = 0.f;
#pragma unroll
    for (int r=0;r<4;r++){
        const int c = lane + 64*r; cc[r]=c; val[r] = (c < FPC);
        float x  = val[r] ? bf2f(crow[c]) : 0.f;
        if (RELU) x = fmaxf(x, 0.f);
        const float w1 = val[r] ? aw_[c]       : 0.f;
        a2[r]          = val[r] ? aw_[FPC + c] : 0.f;
        s1p = fmaf(w1, x, s1p);
    }
    const float s1 = wave_sum(s1p);
    const int base = atom & ~(SEQL-1);
    const float ab = ab_[0];
    float nbr[NBD][4]; float score[NBD]; int idx[NBD];
#pragma unroll
    for (int j=0;j<NBD;j++){
        const int id = adl[atom*NBD + j]; idx[j]=id;
        float s2p = 0.f;
        if (D0) {
            const int bid = bdl[atom*NBD + j];
            const unsigned short* ra = nb1 + (size_t)(base + id)*FPC;
            const unsigned short* rb = nb2 + (size_t)(base + bid)*FPC;
#pragma unroll
            for (int r=0;r<4;r++){
                const float v = val[r] ? leakyf(bf2f(ra[cc[r]]) + bf2f(rb[cc[r]])) : 0.f;
                nbr[j][r]=v; s2p = fmaf(a2[r], v, s2p);
            }
        } else {
            const unsigned short* nrow = nbh + (size_t)(base + id)*FPC;
#pragma unroll
            for (int r=0;r<4;r++){
                const float v = val[r] ? fmaxf(bf2f(nrow[cc[r]]), 0.f) : 0.f;
                nbr[j][r]=v; s2p = fmaf(a2[r], v, s2p);
            }
        }
        const float s2 = wave_sum(s2p);
        float sc = leakyf(s1 + s2 + ab);
        score[j] = sc + (id == SEQL-1 ? NEGV : 0.f);
    }
    float mx = score[0];
#pragma unroll
    for (int j=1;j<NBD;j++) mx = fmaxf(mx, score[j]);
    float e[NBD], sum = 0.f;
#pragma unroll
    for (int j=0;j<NBD;j++){ e[j] = expf(score[j]-mx); sum += e[j]; }
    const float inv = 1.f/sum;
    float w[NBD], saw = 0.f;
#pragma unroll
    for (int j=0;j<NBD;j++){ w[j] = e[j]*inv*(idx[j]==SEQL-1 ? 0.f : 1.f); saw += w[j]; }
#pragma unroll
    for (int r=0;r<4;r++){
        if (val[r]){
            float acc = 0.f;
#pragma unroll
            for (int j=0;j<NBD;j++) acc = fmaf(w[j], nbr[j][r], acc);
            wnbh[(size_t)atom*FPC + cc[r]] = f2bf(acc);
        }
    }
    if (lane==0) s_aw[atom] = saw;
}

// ---------------------------------------------------------------------------
// Mol phase v3: one block (512 thr, 8 waves) per molecule.
// ---------------------------------------------------------------------------
__global__ __launch_bounds__(512)
void mol_fused(const float* __restrict__ hf, const float* __restrict__ amask,
               const float* __restrict__ maw, const float* __restrict__ mab,
               const float* __restrict__ attwT, const float* __restrict__ attb,
               const float* __restrict__ wihT, const float* __restrict__ whhT,
               const float* __restrict__ bih, const float* __restrict__ bhh,
               const float* __restrict__ ow, const float* __restrict__ ob,
               float* __restrict__ out)
{
    __shared__ unsigned short acts[SEQL*FPC];     // 51.2 KB
    __shared__ float part[2][FPC][6];             // 9.6 KB
    __shared__ float molf_s[FPC], amol_s[FPC], wact_s[FPC], mctx_s[FPC];
    __shared__ float s2_s[SEQL], mw_s[SEQL], amk_s[SEQL];
    __shared__ float red[16];
    const int b = blockIdx.x, tid = threadIdx.x;
    const int w = tid >> 6, lane = tid & 63;
    const int half = tid >> 8, c = tid & 255;
    const float* hb = hf + (size_t)b*SEQL*FPC;

    for (int u = tid; u < SEQL*FPC/4; u += 512) {
        const float4 v = *reinterpret_cast<const float4*>(&hb[u*4]);
        acts[u*4+0] = f2bf(fmaxf(v.x, 0.f));
        acts[u*4+1] = f2bf(fmaxf(v.y, 0.f));
        acts[u*4+2] = f2bf(fmaxf(v.z, 0.f));
        acts[u*4+3] = f2bf(fmaxf(v.w, 0.f));
    }
    if (tid < SEQL) amk_s[tid] = amask[b*SEQL + tid];
    __syncthreads();

    if (c < FPC) {
        float s = 0.f;
        for (int l = half*64; l < half*64 + 64; ++l)
            s = fmaf(bf2f(acts[l*FPC + c]), amk_s[l], s);
        part[half][c][0] = s;
    }
    {
        float m2[4];
#pragma unroll
        for (int r=0;r<4;r++){
            const int cc = lane + 64*r;
            m2[r] = (cc < FPC) ? maw[FPC + cc] : 0.f;
        }
        for (int l = w; l < SEQL; l += 8) {
            float s = 0.f;
#pragma unroll
            for (int r=0;r<4;r++){
                const int cc = lane + 64*r;
                if (cc < FPC) s = fmaf(m2[r], bf2f(acts[l*FPC + cc]), s);
            }
            s = wave_sum(s);
            if (lane == 0) s2_s[l] = s;
        }
    }
    __syncthreads();
    if (half == 0 && c < FPC) {
        const float s = part[0][c][0] + part[1][c][0];
        molf_s[c] = s; amol_s[c] = fmaxf(s, 0.f);
    }
    __syncthreads();

    for (int t=0;t<2;t++){
        {
            float v = (tid < FPC) ? maw[tid]*amol_s[tid] : 0.f;
            v = wave_sum(v);
            if (lane == 0) red[w] = v;
        }
        __syncthreads();
        {
            float s1 = 0.f;
#pragma unroll
            for (int i=0;i<8;i++) s1 += red[i];
            if (tid < SEQL)
                mw_s[tid] = leakyf(s1 + s2_s[tid] + mab[0]) + (amk_s[tid]==0.f ? NEGV : 0.f);
        }
        __syncthreads();
        float ev = 0.f;
        if (tid < SEQL) {
            float v = wave_max(mw_s[tid]);
            if (lane == 0) red[8 + w] = v;
        }
        __syncthreads();
        if (tid < SEQL) {
            const float mx = fmaxf(red[8], red[9]);
            ev = expf(mw_s[tid] - mx);
            const float sv = wave_sum(ev);
            if (lane == 0) red[10 + w] = sv;
        }
        __syncthreads();
        if (tid < SEQL) {
            const float inv = 1.f/(red[10] + red[11]);
            const float mv = ev*inv*amk_s[tid];
            mw_s[tid] = mv;
            const float sm = wave_sum(mv);
            if (lane == 0) red[12 + w] = sm;
        }
        __syncthreads();
        const float smw = red[12] + red[13];
        if (c < FPC) {
            float s = 0.f;
            for (int l = half*64; l < half*64 + 64; ++l)
                s = fmaf(mw_s[l], bf2f(acts[l*FPC + c]), s);
            part[half][c][1] = s;
        }
        __syncthreads();
        if (half == 0 && c < FPC) wact_s[c] = part[0][c][1] + part[1][c][1];
        __syncthreads();
        if (c < FPC) {
            float s = 0.f;
            for (int k = half*100; k < half*100 + 100; ++k)
                s = fmaf(wact_s[k], attwT[k*FPC + c], s);
            part[half][c][2] = s;
        }
        __syncthreads();
        if (half == 0 && c < FPC) {
            const float v = part[0][c][2] + part[1][c][2] + smw*attb[c];
            mctx_s[c] = v > 0.f ? v : (expf(v)-1.f);
        }
        __syncthreads();
        if (c < FPC) {
            float g0=0.f,g1=0.f,g2=0.f,g3=0.f,g4=0.f,g5=0.f;
            for (int k = half*100; k < half*100 + 100; ++k){
                const float mc = mctx_s[k], mf = molf_s[k];
                const float* wi = &wihT[k*600];
                const float* wh = &whhT[k*600];
                g0 = fmaf(mc, wi[c],        g0);
                g1 = fmaf(mc, wi[FPC + c],  g1);
                g2 = fmaf(mc, wi[2*FPC + c],g2);
                g3 = fmaf(mf, wh[c],        g3);
                g4 = fmaf(mf, wh[FPC + c],  g4);
                g5 = fmaf(mf, wh[2*FPC + c],g5);
            }
            part[half][c][0]=g0; part[half][c][1]=g1; part[half][c][2]=g2;
            part[half][c][3]=g3; part[half][c][4]=g4; part[half][c][5]=g5;
        }
        __syncthreads();
        float newh = 0.f;
        if (half == 0 && c < FPC) {
            const float gir = part[0][c][0]+part[1][c][0] + bih[c];
            const float giz = part[0][c][1]+part[1][c][1] + bih[FPC+c];
            const float gin = part[0][c][2]+part[1][c][2] + bih[2*FPC+c];
            const float ghr = part[0][c][3]+part[1][c][3] + bhh[c];
            const float ghz = part[0][c][4]+part[1][c][4] + bhh[FPC+c];
            const float ghn = part[0][c][5]+part[1][c][5] + bhh[2*FPC+c];
            const float r = sigm(gir + ghr);
            const float z = sigm(giz + ghz);
            const float n = tanhf(gin + r*ghn);
            newh = (1.f - z)*n + z*molf_s[c];
        }
        __syncthreads();
        if (half == 0 && c < FPC) { molf_s[c] = newh; amol_s[c] = fmaxf(newh, 0.f); }
        __syncthreads();
    }

    {
        float v = (tid < FPC) ? molf_s[tid]*ow[tid] : 0.f;
        v = wave_sum(v);
        if (lane == 0) red[w] = v;
    }
    __syncthreads();
    if (tid == 0) {
        float s = 0.f;
#pragma unroll
        for (int i=0;i<8;i++) s += red[i];
        out[b] = s + ob[0];
    }
}

// ---------------------------------------------------------------------------
extern "C" void kernel_launch(void* const* d_in, const int* in_sizes, int n_in,
                              void* d_out, int out_size, void* d_ws, size_t ws_size,
                              hipStream_t stream)
{
    const float* atom_list = (const float*)d_in[0];
    const float* bond_list = (const float*)d_in[1];
    const int*   adl       = (const int*)d_in[2];
    const int*   bdl       = (const int*)d_in[3];
    const float* amask     = (const float*)d_in[4];
    const float* atom_fc_w = (const float*)d_in[5];
    const float* atom_fc_b = (const float*)d_in[6];
    const float* nb_fc_w   = (const float*)d_in[7];
    const float* nb_fc_b   = (const float*)d_in[8];
    const float* align_w   = (const float*)d_in[9];
    const float* align_b   = (const float*)d_in[10];
    const float* attend_w  = (const float*)d_in[11];
    const float* attend_b  = (const float*)d_in[12];
    const float* gru_wih   = (const float*)d_in[13];
    const float* gru_whh   = (const float*)d_in[14];
    const float* gru_bih   = (const float*)d_in[15];
    const float* gru_bhh   = (const float*)d_in[16];
    const float* mol_align_w  = (const float*)d_in[17];
    const float* mol_align_b  = (const float*)d_in[18];
    const float* mol_attend_w = (const float*)d_in[19];
    const float* mol_attend_b = (const float*)d_in[20];
    const float* mol_gru_wih  = (const float*)d_in[21];
    const float* mol_gru_whh  = (const float*)d_in[22];
    const float* mol_gru_bih  = (const float*)d_in[23];
    const float* mol_gru_bhh  = (const float*)d_in[24];
    const float* output_w  = (const float*)d_in[25];
    const float* output_b  = (const float*)d_in[26];

    float* ws   = (float*)d_ws;
    float* s_aw  = ws;                  // [32768]
    float* attwT = s_aw  + 32768;       // 40000
    float* wihT  = attwT + 40000;       // 120000
    float* whhT  = wihT  + 120000;      // 120000
    float* bpIh  = whhT  + 120000;      // 2304
    float* bpHh  = bpIh  + 2304;        // 2304
    float* wend  = bpHh  + 2304;

    unsigned short* hhA  = (unsigned short*)wend;   // [32768,200] bf16
    unsigned short* hhB  = hhA  + 6553600;
    unsigned short* wnbh = hhB  + 6553600;
    unsigned short* ctxh = wnbh + 6553600;
    unsigned short* aTh  = ctxh + 6553600;          // [32768,200] bf16
    unsigned short* bTh  = aTh  + 6553600;
    unsigned short* w_att = bTh + 6553600;          // 3*200*200
    unsigned short* wpIh  = w_att + 120000;         // 3*768*200
    unsigned short* wpHh  = wpIh + 460800;

    float* outF = (float*)d_out;                    // [32768,200] f32 h (d=2)
    float* outM = outF + (size_t)BL*FPC;            // [256] mol prediction

    const dim3 blk(256);

    // weight prep
    conv_bf<<<(120000+255)/256, blk, 0, stream>>>(attend_w, w_att, 120000);
    conv_perm<<<(3*768*FPC+255)/256, blk, 0, stream>>>(
        gru_wih, gru_whh, gru_bih, gru_bhh, wpIh, wpHh, bpIh, bpHh);
    mol_prep<<<(280000+255)/256, blk, 0, stream>>>(
        mol_attend_w, mol_gru_wih, mol_gru_whh, attwT, wihT, whhT);

    // atom_feature (bf16); aTh = atom@Wa^T (bf16); bTh = bond@Wb^T + b (bf16)
    gemm_bt<1,true,false,true><<<dim3(512,4), blk, 0, stream>>>(
        atom_list, 39, atom_fc_w, 39, atom_fc_b, nullptr, hhA, FPC, BL, FPC, 39);
    gemm_bt<0,false,false,true><<<dim3(512,4), blk, 0, stream>>>(
        atom_list, 39, nb_fc_w, 49, nullptr, nullptr, aTh, FPC, BL, FPC, 39);
    gemm_bt<0,true,false,true><<<dim3(512,4), blk, 0, stream>>>(
        bond_list, 10, nb_fc_w + 39, 49, nb_fc_b, nullptr, bTh, FPC, BL, FPC, 10);

    const unsigned short* hhCur = hhA;
    for (int d=0; d<3; d++) {
        if (d==0)
            attn_radius<true,false><<<BL/4, blk, 0, stream>>>(
                hhA, nullptr, aTh, bTh, adl, bdl, align_w, align_b, wnbh, s_aw);
        else
            attn_radius<false,true><<<BL/4, blk, 0, stream>>>(
                hhCur, hhCur, nullptr, nullptr, adl, nullptr,
                align_w + d*2*FPC, align_b + d, wnbh, s_aw);
        gemm_mfma<2,true><<<dim3(512,2), blk, 0, stream>>>(
            wnbh, FPC, w_att + d*FPC*FPC, FPC, attend_b + d*FPC, s_aw,
            ctxh, FPC, BL, FPC, FPC);
        unsigned short* hhNext = (d==0) ? hhB : ((d==1) ? hhA : nullptr);
        gru_fused<<<dim3(1024), blk, 0, stream>>>(
            ctxh, hhCur, wpIh + d*768*FPC, wpHh + d*768*FPC,
            bpIh + d*768, bpHh + d*768,
            hhNext, (d==2) ? outF : nullptr);
        hhCur = (d==0) ? hhB : hhA;
    }

    // molecule phase reads the f32 h written to d_out
    mol_fused<<<BATCH, 512, 0, stream>>>(
        outF, amask, mol_align_w, mol_align_b, attwT, mol_attend_b,
        wihT, whhT, mol_gru_bih, mol_gru_bhh, output_w, output_b, outM);
}

// Round 10
// 575.270 us; speedup vs baseline: 1.0044x; 1.0044x over previous
//
#include <hip/hip_runtime.h>
#include <cmath>

#define BATCH 256
#define SEQL  128
#define NBD   6
#define FPC   200
#define BL    (BATCH*SEQL)   /* 32768 */
#define NEGV  -9e8f

typedef __attribute__((ext_vector_type(8))) short short8;
typedef __attribute__((ext_vector_type(4))) float f32x4;

__device__ __forceinline__ float wave_sum(float v) {
#pragma unroll
    for (int o = 32; o > 0; o >>= 1) v += __shfl_xor(v, o);
    return v;
}
__device__ __forceinline__ float wave_max(float v) {
#pragma unroll
    for (int o = 32; o > 0; o >>= 1) v = fmaxf(v, __shfl_xor(v, o));
    return v;
}
__device__ __forceinline__ float leakyf(float x){ return x > 0.f ? x : 0.01f*x; }
__device__ __forceinline__ unsigned short f2bf(float f){
    unsigned int x = __float_as_uint(f);
    return (unsigned short)((x + 0x7fffu + ((x >> 16) & 1u)) >> 16);
}
__device__ __forceinline__ float bf2f(unsigned short u){
    return __uint_as_float(((unsigned int)u) << 16);
}
__device__ __forceinline__ float sigm(float x){ return 1.f/(1.f+expf(-x)); }

// ---------------------------------------------------------------------------
// fp32 tiled GEMM: C = act(A@W^T [+ bias]), f32 and/or bf16 outputs.
// ---------------------------------------------------------------------------
template<int ACT, bool BI, bool WF32, bool WBF>
__global__ __launch_bounds__(256)
void gemm_bt(const float* __restrict__ A, int lda,
             const float* __restrict__ W, int ldw,
             const float* __restrict__ bias,
             float* __restrict__ C, unsigned short* __restrict__ Ch, int ldc,
             int M, int N, int K)
{
    __shared__ float As[16][68];
    __shared__ float Ws[16][68];
    const int tid = threadIdx.x;
    const int bm = blockIdx.x * 64;
    const int bn = blockIdx.y * 64;
    const int tx = tid & 15;
    const int ty = tid >> 4;
    const int lr = tid >> 2;
    const int lk = (tid & 3) << 2;
    float acc[4][4] = {};

    for (int k0 = 0; k0 < K; k0 += 16) {
        float a0=0.f,a1=0.f,a2=0.f,a3=0.f, w0=0.f,w1=0.f,w2=0.f,w3=0.f;
        {
            const int rem = K - (k0 + lk);
            const int m = bm + lr;
            if (m < M) {
                const float* p = A + (size_t)m*lda + k0 + lk;
                if (rem > 0) a0 = p[0];
                if (rem > 1) a1 = p[1];
                if (rem > 2) a2 = p[2];
                if (rem > 3) a3 = p[3];
            }
            const int n = bn + lr;
            if (n < N) {
                const float* p = W + (size_t)n*ldw + k0 + lk;
                if (rem > 0) w0 = p[0];
                if (rem > 1) w1 = p[1];
                if (rem > 2) w2 = p[2];
                if (rem > 3) w3 = p[3];
            }
        }
        __syncthreads();
        As[lk+0][lr]=a0; As[lk+1][lr]=a1; As[lk+2][lr]=a2; As[lk+3][lr]=a3;
        Ws[lk+0][lr]=w0; Ws[lk+1][lr]=w1; Ws[lk+2][lr]=w2; Ws[lk+3][lr]=w3;
        __syncthreads();
#pragma unroll
        for (int kk = 0; kk < 16; kk++) {
            const float4 av4 = *reinterpret_cast<const float4*>(&As[kk][ty<<2]);
            const float4 wv4 = *reinterpret_cast<const float4*>(&Ws[kk][tx<<2]);
            const float av[4] = {av4.x, av4.y, av4.z, av4.w};
            const float wv[4] = {wv4.x, wv4.y, wv4.z, wv4.w};
#pragma unroll
            for (int i=0;i<4;i++)
#pragma unroll
                for (int j=0;j<4;j++)
                    acc[i][j] = fmaf(av[i], wv[j], acc[i][j]);
        }
    }
#pragma unroll
    for (int i=0;i<4;i++){
        const int m = bm + (ty<<2) + i;
        if (m >= M) continue;
#pragma unroll
        for (int j=0;j<4;j++){
            const int n = bn + (tx<<2) + j;
            if (n >= N) continue;
            float v = acc[i][j];
            if (BI) v += bias[n];
            if (ACT==1) v = leakyf(v);
            else if (ACT==2) v = v > 0.f ? v : (expf(v)-1.f);
            if (WF32) C[(size_t)m*ldc + n] = v;
            if (WBF)  Ch[(size_t)m*ldc + n] = f2bf(v);
        }
    }
}

// ---------------------------------------------------------------------------
// bf16 MFMA GEMM (attend layer): Ch = elu(A@W^T + bias*rowscale), bf16 out.
// Tile 64x128, 4 waves (2x2). M % 64 == 0, K % 8 == 0.
// ---------------------------------------------------------------------------
template<int ACT, bool RS>
__global__ __launch_bounds__(256)
void gemm_mfma(const unsigned short* __restrict__ A, int lda,
               const unsigned short* __restrict__ W, int ldw,
               const float* __restrict__ bias,
               const float* __restrict__ rowscale,
               unsigned short* __restrict__ Ch, int ldc,
               int M, int N, int K)
{
    __shared__ unsigned short As[64*40];
    __shared__ unsigned short Ws[128*40];
    const int tid = threadIdx.x;
    const int bm = blockIdx.x * 64;
    const int bn = blockIdx.y * 128;
    const int wid = tid >> 6;
    const int lane = tid & 63;
    const int wm = wid >> 1;
    const int wn = wid & 1;
    const int l15 = lane & 15;
    const int kq  = lane >> 4;
    const int koff = kq * 8;

    f32x4 acc[2][4];
#pragma unroll
    for (int i=0;i<2;i++)
#pragma unroll
        for (int j=0;j<4;j++) acc[i][j] = (f32x4){0.f,0.f,0.f,0.f};

    const int sr = tid >> 2;
    const int sk = (tid & 3) * 8;

    for (int k0 = 0; k0 < K; k0 += 32) {
        uint4 av = {0,0,0,0}, wv0 = {0,0,0,0}, wv1 = {0,0,0,0};
        const int kc = k0 + sk;
        if (kc + 8 <= K) {
            av = *reinterpret_cast<const uint4*>(A + (size_t)(bm+sr)*lda + kc);
            const int n0 = bn + sr;
            if (n0 < N) wv0 = *reinterpret_cast<const uint4*>(W + (size_t)n0*ldw + kc);
            const int n1 = bn + sr + 64;
            if (n1 < N) wv1 = *reinterpret_cast<const uint4*>(W + (size_t)n1*ldw + kc);
        }
        __syncthreads();
        *reinterpret_cast<uint4*>(&As[sr*40 + sk]) = av;
        *reinterpret_cast<uint4*>(&Ws[sr*40 + sk]) = wv0;
        *reinterpret_cast<uint4*>(&Ws[(sr+64)*40 + sk]) = wv1;
        __syncthreads();
        short8 af[2], bfr[4];
#pragma unroll
        for (int i=0;i<2;i++)
            af[i] = *reinterpret_cast<const short8*>(&As[(wm*32 + i*16 + l15)*40 + koff]);
#pragma unroll
        for (int j=0;j<4;j++)
            bfr[j] = *reinterpret_cast<const short8*>(&Ws[(wn*64 + j*16 + l15)*40 + koff]);
#pragma unroll
        for (int i=0;i<2;i++)
#pragma unroll
            for (int j=0;j<4;j++)
                acc[i][j] = __builtin_amdgcn_mfma_f32_16x16x32_bf16(af[i], bfr[j], acc[i][j], 0, 0, 0);
    }
#pragma unroll
    for (int i=0;i<2;i++){
        const int mrow0 = bm + wm*32 + i*16 + kq*4;
#pragma unroll
        for (int j=0;j<4;j++){
            const int n = bn + wn*64 + j*16 + l15;
            if (n >= N) continue;
            const float bb = bias[n];
#pragma unroll
            for (int r=0;r<4;r++){
                const int m = mrow0 + r;
                float v = acc[i][j][r] + bb * (RS ? rowscale[m] : 1.f);
                if (ACT==1) v = leakyf(v);
                else if (ACT==2) v = v>0.f ? v : (expf(v)-1.f);
                Ch[(size_t)m*ldc + n] = f2bf(v);
            }
        }
    }
}

// ---------------------------------------------------------------------------
// Fused GRU v4. Grid (1024), 256 thr (4 waves). Per block: 32 rows, all cols.
// LDS stride 232 (29 quads, odd), tail zero-filled. K-loop FULLY UNROLLED
// with double-buffered weight-register prefetch (loads for iter k+1 issued
// before the MFMAs of iter k) -> global load latency hides under MFMA.
// ---------------------------------------------------------------------------
__global__ __launch_bounds__(256, 4)
void gru_fused(const unsigned short* __restrict__ ctxh,
               const unsigned short* __restrict__ hhIn,
               const unsigned short* __restrict__ wpIh,
               const unsigned short* __restrict__ wpHh,
               const float* __restrict__ bpIh,
               const float* __restrict__ bpHh,
               unsigned short* __restrict__ hhOut,
               float* __restrict__ hOutF32)
{
    __shared__ unsigned short A1s[32*232];
    __shared__ unsigned short A2s[32*232];
    const int tid = threadIdx.x;
    const int bm = blockIdx.x * 32;
    const int w = tid >> 6, lane = tid & 63;
    const int l15 = lane & 15, kq = lane >> 4;
    const int koff = kq * 8;
    const short8 zero8 = {0,0,0,0,0,0,0,0};

    for (int u = tid; u < 32*29; u += 256) {
        const int r = u / 29, c = (u % 29) * 8;
        uint4 v1 = {0,0,0,0}, v2 = {0,0,0,0};
        if (c + 8 <= FPC) {
            v1 = *reinterpret_cast<const uint4*>(&ctxh[(size_t)(bm+r)*FPC + c]);
            v2 = *reinterpret_cast<const uint4*>(&hhIn[(size_t)(bm+r)*FPC + c]);
        }
        *reinterpret_cast<uint4*>(&A1s[r*232 + c]) = v1;
        *reinterpret_cast<uint4*>(&A2s[r*232 + c]) = v2;
    }
    __syncthreads();

    for (int p = 0; p < 4; ++p) {
        const int cb = p*4 + w;
        if (cb > 12) break;                 // divergent exit OK: no barriers below
        const int wr0 = cb*48 + l15;
        f32x4 accA[2][3], accB[2][3];
#pragma unroll
        for (int i=0;i<2;i++)
#pragma unroll
            for (int j=0;j<3;j++){
                accA[i][j] = (f32x4){0.f,0.f,0.f,0.f};
                accB[i][j] = (f32x4){0.f,0.f,0.f,0.f};
            }
        // prefetch iter 0 weights (kc = koff <= 24, always valid)
        short8 w1c[3], w2c[3];
#pragma unroll
        for (int j=0;j<3;j++){
            const size_t a = (size_t)(wr0 + j*16)*FPC + koff;
            w1c[j] = *reinterpret_cast<const short8*>(&wpIh[a]);
            w2c[j] = *reinterpret_cast<const short8*>(&wpHh[a]);
        }
#pragma unroll
        for (int it = 0; it < 7; ++it) {
            const int k0 = it*32;
            // prefetch next iteration's weights
            short8 w1n[3], w2n[3];
            if (it < 6) {
                const int kcn = k0 + 32 + koff;
                const bool kval = (kcn + 8 <= FPC);
#pragma unroll
                for (int j=0;j<3;j++){
                    const size_t a = (size_t)(wr0 + j*16)*FPC + kcn;
                    w1n[j] = kval ? *reinterpret_cast<const short8*>(&wpIh[a]) : zero8;
                    w2n[j] = kval ? *reinterpret_cast<const short8*>(&wpHh[a]) : zero8;
                }
            }
            const int kc = k0 + koff;
            short8 a1f[2], a2f[2];
#pragma unroll
            for (int i=0;i<2;i++){
                a1f[i] = *reinterpret_cast<const short8*>(&A1s[(i*16 + l15)*232 + kc]);
                a2f[i] = *reinterpret_cast<const short8*>(&A2s[(i*16 + l15)*232 + kc]);
            }
#pragma unroll
            for (int i=0;i<2;i++)
#pragma unroll
                for (int j=0;j<3;j++){
                    accA[i][j] = __builtin_amdgcn_mfma_f32_16x16x32_bf16(a1f[i], w1c[j], accA[i][j], 0, 0, 0);
                    accB[i][j] = __builtin_amdgcn_mfma_f32_16x16x32_bf16(a2f[i], w2c[j], accB[i][j], 0, 0, 0);
                }
            if (it < 6) {
#pragma unroll
                for (int j=0;j<3;j++){ w1c[j]=w1n[j]; w2c[j]=w2n[j]; }
            }
        }
        const int ch = cb*16 + l15;
        if (ch < FPC) {
            const int p0 = cb*48 + l15;
            const float bi0 = bpIh[p0], bi1 = bpIh[p0+16], bi2 = bpIh[p0+32];
            const float bh0 = bpHh[p0], bh1 = bpHh[p0+16], bh2 = bpHh[p0+32];
#pragma unroll
            for (int i=0;i<2;i++){
#pragma unroll
                for (int r=0;r<4;r++){
                    const int ml = i*16 + kq*4 + r;
                    const int m = bm + ml;
                    const float rr = sigm(accA[i][0][r] + bi0 + accB[i][0][r] + bh0);
                    const float zz = sigm(accA[i][1][r] + bi1 + accB[i][1][r] + bh1);
                    const float nn = tanhf(accA[i][2][r] + bi2 + rr*(accB[i][2][r] + bh2));
                    const float hp = bf2f(A2s[ml*232 + ch]);
                    const float o  = (1.f - zz)*nn + zz*hp;
                    if (hhOut)   hhOut[(size_t)m*FPC + ch] = f2bf(o);
                    if (hOutF32) hOutF32[(size_t)m*FPC + ch] = o;
                }
            }
        }
    }
}

// ---------------------------------------------------------------------------
__global__ __launch_bounds__(256)
void conv_perm(const float* __restrict__ wih, const float* __restrict__ whh,
               const float* __restrict__ bih, const float* __restrict__ bhh,
               unsigned short* __restrict__ wpIh, unsigned short* __restrict__ wpHh,
               float* __restrict__ bpIh, float* __restrict__ bpHh)
{
    const int idx = blockIdx.x*256 + threadIdx.x;
    if (idx >= 3*768*FPC) return;
    const int d = idx / (768*FPC);
    const int rem = idx - d*768*FPC;
    const int pn = rem / FPC;
    const int k = rem - pn*FPC;
    const int cb = pn / 48, w48 = pn % 48;
    const int g = w48 >> 4, ci = w48 & 15;
    const int ch = cb*16 + ci;
    unsigned short vi = 0, vh = 0;
    if (ch < FPC) {
        vi = f2bf(wih[(size_t)d*3*FPC*FPC + (size_t)(g*FPC+ch)*FPC + k]);
        vh = f2bf(whh[(size_t)d*3*FPC*FPC + (size_t)(g*FPC+ch)*FPC + k]);
    }
    wpIh[idx] = vi; wpHh[idx] = vh;
    if (k == 0) {
        bpIh[d*768+pn] = (ch < FPC) ? bih[d*3*FPC + g*FPC + ch] : 0.f;
        bpHh[d*768+pn] = (ch < FPC) ? bhh[d*3*FPC + g*FPC + ch] : 0.f;
    }
}

__global__ __launch_bounds__(256)
void conv_bf(const float* __restrict__ src, unsigned short* __restrict__ dst, int n)
{
    const int i = blockIdx.x*blockDim.x + threadIdx.x;
    if (i < n) dst[i] = f2bf(src[i]);
}

// ---------------------------------------------------------------------------
__global__ __launch_bounds__(256)
void mol_prep(const float* __restrict__ attw, const float* __restrict__ wih,
              const float* __restrict__ whh,
              float* __restrict__ attwT, float* __restrict__ wihT,
              float* __restrict__ whhT)
{
    const int idx = blockIdx.x*256 + threadIdx.x;
    if (idx < 40000) {
        const int o = idx / FPC, k = idx % FPC;
        attwT[k*FPC + o] = attw[o*FPC + k];
    } else if (idx < 160000) {
        const int i = idx - 40000, o = i / FPC, k = i % FPC;
        wihT[k*600 + o] = wih[(size_t)o*FPC + k];
    } else if (idx < 280000) {
        const int i = idx - 160000, o = i / FPC, k = i % FPC;
        whhT[k*600 + o] = whh[(size_t)o*FPC + k];
    }
}

// ---------------------------------------------------------------------------
// Per-atom neighbor attention, bf16 activations. 4 atoms per 256-thr block.
// ---------------------------------------------------------------------------
template<bool D0, bool RELU>
__global__ __launch_bounds__(256)
void attn_radius(const unsigned short* __restrict__ cur,
                 const unsigned short* __restrict__ nbh,
                 const unsigned short* __restrict__ nb1,
                 const unsigned short* __restrict__ nb2,
                 const int* __restrict__ adl, const int* __restrict__ bdl,
                 const float* __restrict__ aw_, const float* __restrict__ ab_,
                 unsigned short* __restrict__ wnbh, float* __restrict__ s_aw)
{
    const int atom = blockIdx.x * 4 + (threadIdx.x >> 6);
    const int lane = threadIdx.x & 63;
    const unsigned short* crow = cur + (size_t)atom*FPC;
    int   cc[4]; bool val[4];
    float a2[4];
    float s1p = 0.f;
#pragma unroll
    for (int r=0;r<4;r++){
        const int c = lane + 64*r; cc[r]=c; val[r] = (c < FPC);
        float x  = val[r] ? bf2f(crow[c]) : 0.f;
        if (RELU) x = fmaxf(x, 0.f);
        const float w1 = val[r] ? aw_[c]       : 0.f;
        a2[r]          = val[r] ? aw_[FPC + c] : 0.f;
        s1p = fmaf(w1, x, s1p);
    }
    const float s1 = wave_sum(s1p);
    const int base = atom & ~(SEQL-1);
    const float ab = ab_[0];
    float nbr[NBD][4]; float score[NBD]; int idx[NBD];
#pragma unroll
    for (int j=0;j<NBD;j++){
        const int id = adl[atom*NBD + j]; idx[j]=id;
        float s2p = 0.f;
        if (D0) {
            const int bid = bdl[atom*NBD + j];
            const unsigned short* ra = nb1 + (size_t)(base + id)*FPC;
            const unsigned short* rb = nb2 + (size_t)(base + bid)*FPC;
#pragma unroll
            for (int r=0;r<4;r++){
                const float v = val[r] ? leakyf(bf2f(ra[cc[r]]) + bf2f(rb[cc[r]])) : 0.f;
                nbr[j][r]=v; s2p = fmaf(a2[r], v, s2p);
            }
        } else {
            const unsigned short* nrow = nbh + (size_t)(base + id)*FPC;
#pragma unroll
            for (int r=0;r<4;r++){
                const float v = val[r] ? fmaxf(bf2f(nrow[cc[r]]), 0.f) : 0.f;
                nbr[j][r]=v; s2p = fmaf(a2[r], v, s2p);
            }
        }
        const float s2 = wave_sum(s2p);
        float sc = leakyf(s1 + s2 + ab);
        score[j] = sc + (id == SEQL-1 ? NEGV : 0.f);
    }
    float mx = score[0];
#pragma unroll
    for (int j=1;j<NBD;j++) mx = fmaxf(mx, score[j]);
    float e[NBD], sum = 0.f;
#pragma unroll
    for (int j=0;j<NBD;j++){ e[j] = expf(score[j]-mx); sum += e[j]; }
    const float inv = 1.f/sum;
    float w[NBD], saw = 0.f;
#pragma unroll
    for (int j=0;j<NBD;j++){ w[j] = e[j]*inv*(idx[j]==SEQL-1 ? 0.f : 1.f); saw += w[j]; }
#pragma unroll
    for (int r=0;r<4;r++){
        if (val[r]){
            float acc = 0.f;
#pragma unroll
            for (int j=0;j<NBD;j++) acc = fmaf(w[j], nbr[j][r], acc);
            wnbh[(size_t)atom*FPC + cc[r]] = f2bf(acc);
        }
    }
    if (lane==0) s_aw[atom] = saw;
}

// ---------------------------------------------------------------------------
// Mol phase v3: one block (512 thr, 8 waves) per molecule.
// ---------------------------------------------------------------------------
__global__ __launch_bounds__(512)
void mol_fused(const float* __restrict__ hf, const float* __restrict__ amask,
               const float* __restrict__ maw, const float* __restrict__ mab,
               const float* __restrict__ attwT, const float* __restrict__ attb,
               const float* __restrict__ wihT, const float* __restrict__ whhT,
               const float* __restrict__ bih, const float* __restrict__ bhh,
               const float* __restrict__ ow, const float* __restrict__ ob,
               float* __restrict__ out)
{
    __shared__ unsigned short acts[SEQL*FPC];     // 51.2 KB
    __shared__ float part[2][FPC][6];             // 9.6 KB
    __shared__ float molf_s[FPC], amol_s[FPC], wact_s[FPC], mctx_s[FPC];
    __shared__ float s2_s[SEQL], mw_s[SEQL], amk_s[SEQL];
    __shared__ float red[16];
    const int b = blockIdx.x, tid = threadIdx.x;
    const int w = tid >> 6, lane = tid & 63;
    const int half = tid >> 8, c = tid & 255;
    const float* hb = hf + (size_t)b*SEQL*FPC;

    for (int u = tid; u < SEQL*FPC/4; u += 512) {
        const float4 v = *reinterpret_cast<const float4*>(&hb[u*4]);
        acts[u*4+0] = f2bf(fmaxf(v.x, 0.f));
        acts[u*4+1] = f2bf(fmaxf(v.y, 0.f));
        acts[u*4+2] = f2bf(fmaxf(v.z, 0.f));
        acts[u*4+3] = f2bf(fmaxf(v.w, 0.f));
    }
    if (tid < SEQL) amk_s[tid] = amask[b*SEQL + tid];
    __syncthreads();

    if (c < FPC) {
        float s = 0.f;
        for (int l = half*64; l < half*64 + 64; ++l)
            s = fmaf(bf2f(acts[l*FPC + c]), amk_s[l], s);
        part[half][c][0] = s;
    }
    {
        float m2[4];
#pragma unroll
        for (int r=0;r<4;r++){
            const int cc = lane + 64*r;
            m2[r] = (cc < FPC) ? maw[FPC + cc] : 0.f;
        }
        for (int l = w; l < SEQL; l += 8) {
            float s = 0.f;
#pragma unroll
            for (int r=0;r<4;r++){
                const int cc = lane + 64*r;
                if (cc < FPC) s = fmaf(m2[r], bf2f(acts[l*FPC + cc]), s);
            }
            s = wave_sum(s);
            if (lane == 0) s2_s[l] = s;
        }
    }
    __syncthreads();
    if (half == 0 && c < FPC) {
        const float s = part[0][c][0] + part[1][c][0];
        molf_s[c] = s; amol_s[c] = fmaxf(s, 0.f);
    }
    __syncthreads();

    for (int t=0;t<2;t++){
        {
            float v = (tid < FPC) ? maw[tid]*amol_s[tid] : 0.f;
            v = wave_sum(v);
            if (lane == 0) red[w] = v;
        }
        __syncthreads();
        {
            float s1 = 0.f;
#pragma unroll
            for (int i=0;i<8;i++) s1 += red[i];
            if (tid < SEQL)
                mw_s[tid] = leakyf(s1 + s2_s[tid] + mab[0]) + (amk_s[tid]==0.f ? NEGV : 0.f);
        }
        __syncthreads();
        float ev = 0.f;
        if (tid < SEQL) {
            float v = wave_max(mw_s[tid]);
            if (lane == 0) red[8 + w] = v;
        }
        __syncthreads();
        if (tid < SEQL) {
            const float mx = fmaxf(red[8], red[9]);
            ev = expf(mw_s[tid] - mx);
            const float sv = wave_sum(ev);
            if (lane == 0) red[10 + w] = sv;
        }
        __syncthreads();
        if (tid < SEQL) {
            const float inv = 1.f/(red[10] + red[11]);
            const float mv = ev*inv*amk_s[tid];
            mw_s[tid] = mv;
            const float sm = wave_sum(mv);
            if (lane == 0) red[12 + w] = sm;
        }
        __syncthreads();
        const float smw = red[12] + red[13];
        if (c < FPC) {
            float s = 0.f;
            for (int l = half*64; l < half*64 + 64; ++l)
                s = fmaf(mw_s[l], bf2f(acts[l*FPC + c]), s);
            part[half][c][1] = s;
        }
        __syncthreads();
        if (half == 0 && c < FPC) wact_s[c] = part[0][c][1] + part[1][c][1];
        __syncthreads();
        if (c < FPC) {
            float s = 0.f;
            for (int k = half*100; k < half*100 + 100; ++k)
                s = fmaf(wact_s[k], attwT[k*FPC + c], s);
            part[half][c][2] = s;
        }
        __syncthreads();
        if (half == 0 && c < FPC) {
            const float v = part[0][c][2] + part[1][c][2] + smw*attb[c];
            mctx_s[c] = v > 0.f ? v : (expf(v)-1.f);
        }
        __syncthreads();
        if (c < FPC) {
            float g0=0.f,g1=0.f,g2=0.f,g3=0.f,g4=0.f,g5=0.f;
            for (int k = half*100; k < half*100 + 100; ++k){
                const float mc = mctx_s[k], mf = molf_s[k];
                const float* wi = &wihT[k*600];
                const float* wh = &whhT[k*600];
                g0 = fmaf(mc, wi[c],        g0);
                g1 = fmaf(mc, wi[FPC + c],  g1);
                g2 = fmaf(mc, wi[2*FPC + c],g2);
                g3 = fmaf(mf, wh[c],        g3);
                g4 = fmaf(mf, wh[FPC + c],  g4);
                g5 = fmaf(mf, wh[2*FPC + c],g5);
            }
            part[half][c][0]=g0; part[half][c][1]=g1; part[half][c][2]=g2;
            part[half][c][3]=g3; part[half][c][4]=g4; part[half][c][5]=g5;
        }
        __syncthreads();
        float newh = 0.f;
        if (half == 0 && c < FPC) {
            const float gir = part[0][c][0]+part[1][c][0] + bih[c];
            const float giz = part[0][c][1]+part[1][c][1] + bih[FPC+c];
            const float gin = part[0][c][2]+part[1][c][2] + bih[2*FPC+c];
            const float ghr = part[0][c][3]+part[1][c][3] + bhh[c];
            const float ghz = part[0][c][4]+part[1][c][4] + bhh[FPC+c];
            const float ghn = part[0][c][5]+part[1][c][5] + bhh[2*FPC+c];
            const float r = sigm(gir + ghr);
            const float z = sigm(giz + ghz);
            const float n = tanhf(gin + r*ghn);
            newh = (1.f - z)*n + z*molf_s[c];
        }
        __syncthreads();
        if (half == 0 && c < FPC) { molf_s[c] = newh; amol_s[c] = fmaxf(newh, 0.f); }
        __syncthreads();
    }

    {
        float v = (tid < FPC) ? molf_s[tid]*ow[tid] : 0.f;
        v = wave_sum(v);
        if (lane == 0) red[w] = v;
    }
    __syncthreads();
    if (tid == 0) {
        float s = 0.f;
#pragma unroll
        for (int i=0;i<8;i++) s += red[i];
        out[b] = s + ob[0];
    }
}

// ---------------------------------------------------------------------------
extern "C" void kernel_launch(void* const* d_in, const int* in_sizes, int n_in,
                              void* d_out, int out_size, void* d_ws, size_t ws_size,
                              hipStream_t stream)
{
    const float* atom_list = (const float*)d_in[0];
    const float* bond_list = (const float*)d_in[1];
    const int*   adl       = (const int*)d_in[2];
    const int*   bdl       = (const int*)d_in[3];
    const float* amask     = (const float*)d_in[4];
    const float* atom_fc_w = (const float*)d_in[5];
    const float* atom_fc_b = (const float*)d_in[6];
    const float* nb_fc_w   = (const float*)d_in[7];
    const float* nb_fc_b   = (const float*)d_in[8];
    const float* align_w   = (const float*)d_in[9];
    const float* align_b   = (const float*)d_in[10];
    const float* attend_w  = (const float*)d_in[11];
    const float* attend_b  = (const float*)d_in[12];
    const float* gru_wih   = (const float*)d_in[13];
    const float* gru_whh   = (const float*)d_in[14];
    const float* gru_bih   = (const float*)d_in[15];
    const float* gru_bhh   = (const float*)d_in[16];
    const float* mol_align_w  = (const float*)d_in[17];
    const float* mol_align_b  = (const float*)d_in[18];
    const float* mol_attend_w = (const float*)d_in[19];
    const float* mol_attend_b = (const float*)d_in[20];
    const float* mol_gru_wih  = (const float*)d_in[21];
    const float* mol_gru_whh  = (const float*)d_in[22];
    const float* mol_gru_bih  = (const float*)d_in[23];
    const float* mol_gru_bhh  = (const float*)d_in[24];
    const float* output_w  = (const float*)d_in[25];
    const float* output_b  = (const float*)d_in[26];

    float* ws   = (float*)d_ws;
    float* s_aw  = ws;                  // [32768]
    float* attwT = s_aw  + 32768;       // 40000
    float* wihT  = attwT + 40000;       // 120000
    float* whhT  = wihT  + 120000;      // 120000
    float* bpIh  = whhT  + 120000;      // 2304
    float* bpHh  = bpIh  + 2304;        // 2304
    float* wend  = bpHh  + 2304;

    unsigned short* hhA  = (unsigned short*)wend;   // [32768,200] bf16
    unsigned short* hhB  = hhA  + 6553600;
    unsigned short* wnbh = hhB  + 6553600;
    unsigned short* ctxh = wnbh + 6553600;
    unsigned short* aTh  = ctxh + 6553600;          // [32768,200] bf16
    unsigned short* bTh  = aTh  + 6553600;
    unsigned short* w_att = bTh + 6553600;          // 3*200*200
    unsigned short* wpIh  = w_att + 120000;         // 3*768*200
    unsigned short* wpHh  = wpIh + 460800;

    float* outF = (float*)d_out;                    // [32768,200] f32 h (d=2)
    float* outM = outF + (size_t)BL*FPC;            // [256] mol prediction

    const dim3 blk(256);

    // weight prep
    conv_bf<<<(120000+255)/256, blk, 0, stream>>>(attend_w, w_att, 120000);
    conv_perm<<<(3*768*FPC+255)/256, blk, 0, stream>>>(
        gru_wih, gru_whh, gru_bih, gru_bhh, wpIh, wpHh, bpIh, bpHh);
    mol_prep<<<(280000+255)/256, blk, 0, stream>>>(
        mol_attend_w, mol_gru_wih, mol_gru_whh, attwT, wihT, whhT);

    // atom_feature (bf16); aTh = atom@Wa^T (bf16); bTh = bond@Wb^T + b (bf16)
    gemm_bt<1,true,false,true><<<dim3(512,4), blk, 0, stream>>>(
        atom_list, 39, atom_fc_w, 39, atom_fc_b, nullptr, hhA, FPC, BL, FPC, 39);
    gemm_bt<0,false,false,true><<<dim3(512,4), blk, 0, stream>>>(
        atom_list, 39, nb_fc_w, 49, nullptr, nullptr, aTh, FPC, BL, FPC, 39);
    gemm_bt<0,true,false,true><<<dim3(512,4), blk, 0, stream>>>(
        bond_list, 10, nb_fc_w + 39, 49, nb_fc_b, nullptr, bTh, FPC, BL, FPC, 10);

    const unsigned short* hhCur = hhA;
    for (int d=0; d<3; d++) {
        if (d==0)
            attn_radius<true,false><<<BL/4, blk, 0, stream>>>(
                hhA, nullptr, aTh, bTh, adl, bdl, align_w, align_b, wnbh, s_aw);
        else
            attn_radius<false,true><<<BL/4, blk, 0, stream>>>(
                hhCur, hhCur, nullptr, nullptr, adl, nullptr,
                align_w + d*2*FPC, align_b + d, wnbh, s_aw);
        gemm_mfma<2,true><<<dim3(512,2), blk, 0, stream>>>(
            wnbh, FPC, w_att + d*FPC*FPC, FPC, attend_b + d*FPC, s_aw,
            ctxh, FPC, BL, FPC, FPC);
        unsigned short* hhNext = (d==0) ? hhB : ((d==1) ? hhA : nullptr);
        gru_fused<<<dim3(1024), blk, 0, stream>>>(
            ctxh, hhCur, wpIh + d*768*FPC, wpHh + d*768*FPC,
            bpIh + d*768, bpHh + d*768,
            hhNext, (d==2) ? outF : nullptr);
        hhCur = (d==0) ? hhB : hhA;
    }

    // molecule phase reads the f32 h written to d_out
    mol_fused<<<BATCH, 512, 0, stream>>>(
        outF, amask, mol_align_w, mol_align_b, attwT, mol_attend_b,
        wihT, whhT, mol_gru_bih, mol_gru_bhh, output_w, output_b, outM);
}

// Round 12
// 482.271 us; speedup vs baseline: 1.1980x; 1.1928x over previous
//
#include <hip/hip_runtime.h>
#include <cmath>

#define BATCH 256
#define SEQL  128
#define NBD   6
#define FPC   200
#define BL    (BATCH*SEQL)   /* 32768 */
#define NEGV  -9e8f

typedef __attribute__((ext_vector_type(8))) short short8;
typedef __attribute__((ext_vector_type(4))) float f32x4;

__device__ __forceinline__ float wave_sum(float v) {
#pragma unroll
    for (int o = 32; o > 0; o >>= 1) v += __shfl_xor(v, o);
    return v;
}
__device__ __forceinline__ float wave_max(float v) {
#pragma unroll
    for (int o = 32; o > 0; o >>= 1) v = fmaxf(v, __shfl_xor(v, o));
    return v;
}
__device__ __forceinline__ float leakyf(float x){ return x > 0.f ? x : 0.01f*x; }
__device__ __forceinline__ unsigned short f2bf(float f){
    unsigned int x = __float_as_uint(f);
    return (unsigned short)((x + 0x7fffu + ((x >> 16) & 1u)) >> 16);
}
__device__ __forceinline__ float bf2f(unsigned short u){
    return __uint_as_float(((unsigned int)u) << 16);
}
__device__ __forceinline__ float sigm(float x){ return 1.f/(1.f+expf(-x)); }

// ---------------------------------------------------------------------------
// fp32 tiled GEMM: C = act(A@W^T [+ bias]), f32 and/or bf16 outputs.
// ---------------------------------------------------------------------------
template<int ACT, bool BI, bool WF32, bool WBF>
__global__ __launch_bounds__(256)
void gemm_bt(const float* __restrict__ A, int lda,
             const float* __restrict__ W, int ldw,
             const float* __restrict__ bias,
             float* __restrict__ C, unsigned short* __restrict__ Ch, int ldc,
             int M, int N, int K)
{
    __shared__ float As[16][68];
    __shared__ float Ws[16][68];
    const int tid = threadIdx.x;
    const int bm = blockIdx.x * 64;
    const int bn = blockIdx.y * 64;
    const int tx = tid & 15;
    const int ty = tid >> 4;
    const int lr = tid >> 2;
    const int lk = (tid & 3) << 2;
    float acc[4][4] = {};

    for (int k0 = 0; k0 < K; k0 += 16) {
        float a0=0.f,a1=0.f,a2=0.f,a3=0.f, w0=0.f,w1=0.f,w2=0.f,w3=0.f;
        {
            const int rem = K - (k0 + lk);
            const int m = bm + lr;
            if (m < M) {
                const float* p = A + (size_t)m*lda + k0 + lk;
                if (rem > 0) a0 = p[0];
                if (rem > 1) a1 = p[1];
                if (rem > 2) a2 = p[2];
                if (rem > 3) a3 = p[3];
            }
            const int n = bn + lr;
            if (n < N) {
                const float* p = W + (size_t)n*ldw + k0 + lk;
                if (rem > 0) w0 = p[0];
                if (rem > 1) w1 = p[1];
                if (rem > 2) w2 = p[2];
                if (rem > 3) w3 = p[3];
            }
        }
        __syncthreads();
        As[lk+0][lr]=a0; As[lk+1][lr]=a1; As[lk+2][lr]=a2; As[lk+3][lr]=a3;
        Ws[lk+0][lr]=w0; Ws[lk+1][lr]=w1; Ws[lk+2][lr]=w2; Ws[lk+3][lr]=w3;
        __syncthreads();
#pragma unroll
        for (int kk = 0; kk < 16; kk++) {
            const float4 av4 = *reinterpret_cast<const float4*>(&As[kk][ty<<2]);
            const float4 wv4 = *reinterpret_cast<const float4*>(&Ws[kk][tx<<2]);
            const float av[4] = {av4.x, av4.y, av4.z, av4.w};
            const float wv[4] = {wv4.x, wv4.y, wv4.z, wv4.w};
#pragma unroll
            for (int i=0;i<4;i++)
#pragma unroll
                for (int j=0;j<4;j++)
                    acc[i][j] = fmaf(av[i], wv[j], acc[i][j]);
        }
    }
#pragma unroll
    for (int i=0;i<4;i++){
        const int m = bm + (ty<<2) + i;
        if (m >= M) continue;
#pragma unroll
        for (int j=0;j<4;j++){
            const int n = bn + (tx<<2) + j;
            if (n >= N) continue;
            float v = acc[i][j];
            if (BI) v += bias[n];
            if (ACT==1) v = leakyf(v);
            else if (ACT==2) v = v > 0.f ? v : (expf(v)-1.f);
            if (WF32) C[(size_t)m*ldc + n] = v;
            if (WBF)  Ch[(size_t)m*ldc + n] = f2bf(v);
        }
    }
}

// ---------------------------------------------------------------------------
// bf16 MFMA GEMM (attend layer): Ch = elu(A@W^T + bias*rowscale), bf16 out.
// Tile 64x128, 4 waves (2x2). M % 64 == 0, K % 8 == 0.
// ---------------------------------------------------------------------------
template<int ACT, bool RS>
__global__ __launch_bounds__(256)
void gemm_mfma(const unsigned short* __restrict__ A, int lda,
               const unsigned short* __restrict__ W, int ldw,
               const float* __restrict__ bias,
               const float* __restrict__ rowscale,
               unsigned short* __restrict__ Ch, int ldc,
               int M, int N, int K)
{
    __shared__ unsigned short As[64*40];
    __shared__ unsigned short Ws[128*40];
    const int tid = threadIdx.x;
    const int bm = blockIdx.x * 64;
    const int bn = blockIdx.y * 128;
    const int wid = tid >> 6;
    const int lane = tid & 63;
    const int wm = wid >> 1;
    const int wn = wid & 1;
    const int l15 = lane & 15;
    const int kq  = lane >> 4;
    const int koff = kq * 8;

    f32x4 acc[2][4];
#pragma unroll
    for (int i=0;i<2;i++)
#pragma unroll
        for (int j=0;j<4;j++) acc[i][j] = (f32x4){0.f,0.f,0.f,0.f};

    const int sr = tid >> 2;
    const int sk = (tid & 3) * 8;

    for (int k0 = 0; k0 < K; k0 += 32) {
        uint4 av = {0,0,0,0}, wv0 = {0,0,0,0}, wv1 = {0,0,0,0};
        const int kc = k0 + sk;
        if (kc + 8 <= K) {
            av = *reinterpret_cast<const uint4*>(A + (size_t)(bm+sr)*lda + kc);
            const int n0 = bn + sr;
            if (n0 < N) wv0 = *reinterpret_cast<const uint4*>(W + (size_t)n0*ldw + kc);
            const int n1 = bn + sr + 64;
            if (n1 < N) wv1 = *reinterpret_cast<const uint4*>(W + (size_t)n1*ldw + kc);
        }
        __syncthreads();
        *reinterpret_cast<uint4*>(&As[sr*40 + sk]) = av;
        *reinterpret_cast<uint4*>(&Ws[sr*40 + sk]) = wv0;
        *reinterpret_cast<uint4*>(&Ws[(sr+64)*40 + sk]) = wv1;
        __syncthreads();
        short8 af[2], bfr[4];
#pragma unroll
        for (int i=0;i<2;i++)
            af[i] = *reinterpret_cast<const short8*>(&As[(wm*32 + i*16 + l15)*40 + koff]);
#pragma unroll
        for (int j=0;j<4;j++)
            bfr[j] = *reinterpret_cast<const short8*>(&Ws[(wn*64 + j*16 + l15)*40 + koff]);
#pragma unroll
        for (int i=0;i<2;i++)
#pragma unroll
            for (int j=0;j<4;j++)
                acc[i][j] = __builtin_amdgcn_mfma_f32_16x16x32_bf16(af[i], bfr[j], acc[i][j], 0, 0, 0);
    }
#pragma unroll
    for (int i=0;i<2;i++){
        const int mrow0 = bm + wm*32 + i*16 + kq*4;
#pragma unroll
        for (int j=0;j<4;j++){
            const int n = bn + wn*64 + j*16 + l15;
            if (n >= N) continue;
            const float bb = bias[n];
#pragma unroll
            for (int r=0;r<4;r++){
                const int m = mrow0 + r;
                float v = acc[i][j][r] + bb * (RS ? rowscale[m] : 1.f);
                if (ACT==1) v = leakyf(v);
                else if (ACT==2) v = v>0.f ? v : (expf(v)-1.f);
                Ch[(size_t)m*ldc + n] = f2bf(v);
            }
        }
    }
}

// ---------------------------------------------------------------------------
// Fused GRU v5. Grid (512), 256 thr (4 waves). Per block: 64 rows, all cols.
// Each wave strides panels cb = w + 4*pp; per K-iter: 6 weight loads feed
// 24 MFMAs over 4 row-fragments (2x the latency cover of v4, half the
// per-dispatch weight re-reads). LDS stride 232 (odd quads, conflict-free),
// tail zero-filled. No barriers in compute loop.
// ---------------------------------------------------------------------------
__global__ __launch_bounds__(256, 2)
void gru_fused(const unsigned short* __restrict__ ctxh,
               const unsigned short* __restrict__ hhIn,
               const unsigned short* __restrict__ wpIh,
               const unsigned short* __restrict__ wpHh,
               const float* __restrict__ bpIh,
               const float* __restrict__ bpHh,
               unsigned short* __restrict__ hhOut,
               float* __restrict__ hOutF32)
{
    __shared__ unsigned short A1s[64*232];
    __shared__ unsigned short A2s[64*232];
    const int tid = threadIdx.x;
    const int bm = blockIdx.x * 64;
    const int w = tid >> 6, lane = tid & 63;
    const int l15 = lane & 15, kq = lane >> 4;
    const int koff = kq * 8;
    const short8 zero8 = {0,0,0,0,0,0,0,0};

    for (int u = tid; u < 64*29; u += 256) {
        const int r = u / 29, c = (u % 29) * 8;
        uint4 v1 = {0,0,0,0}, v2 = {0,0,0,0};
        if (c + 8 <= FPC) {
            v1 = *reinterpret_cast<const uint4*>(&ctxh[(size_t)(bm+r)*FPC + c]);
            v2 = *reinterpret_cast<const uint4*>(&hhIn[(size_t)(bm+r)*FPC + c]);
        }
        *reinterpret_cast<uint4*>(&A1s[r*232 + c]) = v1;
        *reinterpret_cast<uint4*>(&A2s[r*232 + c]) = v2;
    }
    __syncthreads();

    for (int pp = 0; pp < 4; ++pp) {
        const int cb = w + pp*4;
        if (cb > 12) break;                 // divergent exit OK: no barriers below
        const int wr0 = cb*48 + l15;
        f32x4 accA[4][3], accB[4][3];       // [rowfrag][gate]
#pragma unroll
        for (int i=0;i<4;i++)
#pragma unroll
            for (int j=0;j<3;j++){
                accA[i][j] = (f32x4){0.f,0.f,0.f,0.f};
                accB[i][j] = (f32x4){0.f,0.f,0.f,0.f};
            }
#pragma unroll
        for (int it = 0; it < 7; ++it) {
            const int kc = it*32 + koff;
            const bool kval = (kc + 8 <= FPC);
            short8 w1f[3], w2f[3];
#pragma unroll
            for (int j=0;j<3;j++){
                const size_t a = (size_t)(wr0 + j*16)*FPC + kc;
                w1f[j] = kval ? *reinterpret_cast<const short8*>(&wpIh[a]) : zero8;
                w2f[j] = kval ? *reinterpret_cast<const short8*>(&wpHh[a]) : zero8;
            }
            short8 a1f[4], a2f[4];
#pragma unroll
            for (int i=0;i<4;i++){
                a1f[i] = *reinterpret_cast<const short8*>(&A1s[(i*16 + l15)*232 + kc]);
                a2f[i] = *reinterpret_cast<const short8*>(&A2s[(i*16 + l15)*232 + kc]);
            }
#pragma unroll
            for (int i=0;i<4;i++)
#pragma unroll
                for (int j=0;j<3;j++){
                    accA[i][j] = __builtin_amdgcn_mfma_f32_16x16x32_bf16(a1f[i], w1f[j], accA[i][j], 0, 0, 0);
                    accB[i][j] = __builtin_amdgcn_mfma_f32_16x16x32_bf16(a2f[i], w2f[j], accB[i][j], 0, 0, 0);
                }
        }
        const int ch = cb*16 + l15;
        if (ch < FPC) {
            const int p0 = cb*48 + l15;
            const float bi0 = bpIh[p0], bi1 = bpIh[p0+16], bi2 = bpIh[p0+32];
            const float bh0 = bpHh[p0], bh1 = bpHh[p0+16], bh2 = bpHh[p0+32];
#pragma unroll
            for (int i=0;i<4;i++){
#pragma unroll
                for (int r=0;r<4;r++){
                    const int ml = i*16 + kq*4 + r;
                    const int m = bm + ml;
                    const float rr = sigm(accA[i][0][r] + bi0 + accB[i][0][r] + bh0);
                    const float zz = sigm(accA[i][1][r] + bi1 + accB[i][1][r] + bh1);
                    const float nn = tanhf(accA[i][2][r] + bi2 + rr*(accB[i][2][r] + bh2));
                    const float hp = bf2f(A2s[ml*232 + ch]);
                    const float o  = (1.f - zz)*nn + zz*hp;
                    if (hhOut)   hhOut[(size_t)m*FPC + ch] = f2bf(o);
                    if (hOutF32) hOutF32[(size_t)m*FPC + ch] = o;
                }
            }
        }
    }
}

// ---------------------------------------------------------------------------
__global__ __launch_bounds__(256)
void conv_perm(const float* __restrict__ wih, const float* __restrict__ whh,
               const float* __restrict__ bih, const float* __restrict__ bhh,
               unsigned short* __restrict__ wpIh, unsigned short* __restrict__ wpHh,
               float* __restrict__ bpIh, float* __restrict__ bpHh)
{
    const int idx = blockIdx.x*256 + threadIdx.x;
    if (idx >= 3*768*FPC) return;
    const int d = idx / (768*FPC);
    const int rem = idx - d*768*FPC;
    const int pn = rem / FPC;
    const int k = rem - pn*FPC;
    const int cb = pn / 48, w48 = pn % 48;
    const int g = w48 >> 4, ci = w48 & 15;
    const int ch = cb*16 + ci;
    unsigned short vi = 0, vh = 0;
    if (ch < FPC) {
        vi = f2bf(wih[(size_t)d*3*FPC*FPC + (size_t)(g*FPC+ch)*FPC + k]);
        vh = f2bf(whh[(size_t)d*3*FPC*FPC + (size_t)(g*FPC+ch)*FPC + k]);
    }
    wpIh[idx] = vi; wpHh[idx] = vh;
    if (k == 0) {
        bpIh[d*768+pn] = (ch < FPC) ? bih[d*3*FPC + g*FPC + ch] : 0.f;
        bpHh[d*768+pn] = (ch < FPC) ? bhh[d*3*FPC + g*FPC + ch] : 0.f;
    }
}

__global__ __launch_bounds__(256)
void conv_bf(const float* __restrict__ src, unsigned short* __restrict__ dst, int n)
{
    const int i = blockIdx.x*blockDim.x + threadIdx.x;
    if (i < n) dst[i] = f2bf(src[i]);
}

// ---------------------------------------------------------------------------
__global__ __launch_bounds__(256)
void mol_prep(const float* __restrict__ attw, const float* __restrict__ wih,
              const float* __restrict__ whh,
              float* __restrict__ attwT, float* __restrict__ wihT,
              float* __restrict__ whhT)
{
    const int idx = blockIdx.x*256 + threadIdx.x;
    if (idx < 40000) {
        const int o = idx / FPC, k = idx % FPC;
        attwT[k*FPC + o] = attw[o*FPC + k];
    } else if (idx < 160000) {
        const int i = idx - 40000, o = i / FPC, k = i % FPC;
        wihT[k*600 + o] = wih[(size_t)o*FPC + k];
    } else if (idx < 280000) {
        const int i = idx - 160000, o = i / FPC, k = i % FPC;
        whhT[k*600 + o] = whh[(size_t)o*FPC + k];
    }
}

// ---------------------------------------------------------------------------
// Per-atom neighbor attention, bf16 activations. 4 atoms per 256-thr block.
// ---------------------------------------------------------------------------
template<bool D0, bool RELU>
__global__ __launch_bounds__(256)
void attn_radius(const unsigned short* __restrict__ cur,
                 const unsigned short* __restrict__ nbh,
                 const unsigned short* __restrict__ nb1,
                 const unsigned short* __restrict__ nb2,
                 const int* __restrict__ adl, const int* __restrict__ bdl,
                 const float* __restrict__ aw_, const float* __restrict__ ab_,
                 unsigned short* __restrict__ wnbh, float* __restrict__ s_aw)
{
    const int atom = blockIdx.x * 4 + (threadIdx.x >> 6);
    const int lane = threadIdx.x & 63;
    const unsigned short* crow = cur + (size_t)atom*FPC;
    int   cc[4]; bool val[4];
    float a2[4];
    float s1p = 0.f;
#pragma unroll
    for (int r=0;r<4;r++){
        const int c = lane + 64*r; cc[r]=c; val[r] = (c < FPC);
        float x  = val[r] ? bf2f(crow[c]) : 0.f;
        if (RELU) x = fmaxf(x, 0.f);
        const float w1 = val[r] ? aw_[c]       : 0.f;
        a2[r]          = val[r] ? aw_[FPC + c] : 0.f;
        s1p = fmaf(w1, x, s1p);
    }
    const float s1 = wave_sum(s1p);
    const int base = atom & ~(SEQL-1);
    const float ab = ab_[0];
    float nbr[NBD][4]; float score[NBD]; int idx[NBD];
#pragma unroll
    for (int j=0;j<NBD;j++){
        const int id = adl[atom*NBD + j]; idx[j]=id;
        float s2p = 0.f;
        if (D0) {
            const int bid = bdl[atom*NBD + j];
            const unsigned short* ra = nb1 + (size_t)(base + id)*FPC;
            const unsigned short* rb = nb2 + (size_t)(base + bid)*FPC;
#pragma unroll
            for (int r=0;r<4;r++){
                const float v = val[r] ? leakyf(bf2f(ra[cc[r]]) + bf2f(rb[cc[r]])) : 0.f;
                nbr[j][r]=v; s2p = fmaf(a2[r], v, s2p);
            }
        } else {
            const unsigned short* nrow = nbh + (size_t)(base + id)*FPC;
#pragma unroll
            for (int r=0;r<4;r++){
                const float v = val[r] ? fmaxf(bf2f(nrow[cc[r]]), 0.f) : 0.f;
                nbr[j][r]=v; s2p = fmaf(a2[r], v, s2p);
            }
        }
        const float s2 = wave_sum(s2p);
        float sc = leakyf(s1 + s2 + ab);
        score[j] = sc + (id == SEQL-1 ? NEGV : 0.f);
    }
    float mx = score[0];
#pragma unroll
    for (int j=1;j<NBD;j++) mx = fmaxf(mx, score[j]);
    float e[NBD], sum = 0.f;
#pragma unroll
    for (int j=0;j<NBD;j++){ e[j] = expf(score[j]-mx); sum += e[j]; }
    const float inv = 1.f/sum;
    float w[NBD], saw = 0.f;
#pragma unroll
    for (int j=0;j<NBD;j++){ w[j] = e[j]*inv*(idx[j]==SEQL-1 ? 0.f : 1.f); saw += w[j]; }
#pragma unroll
    for (int r=0;r<4;r++){
        if (val[r]){
            float acc = 0.f;
#pragma unroll
            for (int j=0;j<NBD;j++) acc = fmaf(w[j], nbr[j][r], acc);
            wnbh[(size_t)atom*FPC + cc[r]] = f2bf(acc);
        }
    }
    if (lane==0) s_aw[atom] = saw;
}

// ---------------------------------------------------------------------------
// Mol phase v3: one block (512 thr, 8 waves) per molecule.
// ---------------------------------------------------------------------------
__global__ __launch_bounds__(512)
void mol_fused(const float* __restrict__ hf, const float* __restrict__ amask,
               const float* __restrict__ maw, const float* __restrict__ mab,
               const float* __restrict__ attwT, const float* __restrict__ attb,
               const float* __restrict__ wihT, const float* __restrict__ whhT,
               const float* __restrict__ bih, const float* __restrict__ bhh,
               const float* __restrict__ ow, const float* __restrict__ ob,
               float* __restrict__ out)
{
    __shared__ unsigned short acts[SEQL*FPC];     // 51.2 KB
    __shared__ float part[2][FPC][6];             // 9.6 KB
    __shared__ float molf_s[FPC], amol_s[FPC], wact_s[FPC], mctx_s[FPC];
    __shared__ float s2_s[SEQL], mw_s[SEQL], amk_s[SEQL];
    __shared__ float red[16];
    const int b = blockIdx.x, tid = threadIdx.x;
    const int w = tid >> 6, lane = tid & 63;
    const int half = tid >> 8, c = tid & 255;
    const float* hb = hf + (size_t)b*SEQL*FPC;

    for (int u = tid; u < SEQL*FPC/4; u += 512) {
        const float4 v = *reinterpret_cast<const float4*>(&hb[u*4]);
        acts[u*4+0] = f2bf(fmaxf(v.x, 0.f));
        acts[u*4+1] = f2bf(fmaxf(v.y, 0.f));
        acts[u*4+2] = f2bf(fmaxf(v.z, 0.f));
        acts[u*4+3] = f2bf(fmaxf(v.w, 0.f));
    }
    if (tid < SEQL) amk_s[tid] = amask[b*SEQL + tid];
    __syncthreads();

    if (c < FPC) {
        float s = 0.f;
        for (int l = half*64; l < half*64 + 64; ++l)
            s = fmaf(bf2f(acts[l*FPC + c]), amk_s[l], s);
        part[half][c][0] = s;
    }
    {
        float m2[4];
#pragma unroll
        for (int r=0;r<4;r++){
            const int cc = lane + 64*r;
            m2[r] = (cc < FPC) ? maw[FPC + cc] : 0.f;
        }
        for (int l = w; l < SEQL; l += 8) {
            float s = 0.f;
#pragma unroll
            for (int r=0;r<4;r++){
                const int cc = lane + 64*r;
                if (cc < FPC) s = fmaf(m2[r], bf2f(acts[l*FPC + cc]), s);
            }
            s = wave_sum(s);
            if (lane == 0) s2_s[l] = s;
        }
    }
    __syncthreads();
    if (half == 0 && c < FPC) {
        const float s = part[0][c][0] + part[1][c][0];
        molf_s[c] = s; amol_s[c] = fmaxf(s, 0.f);
    }
    __syncthreads();

    for (int t=0;t<2;t++){
        {
            float v = (tid < FPC) ? maw[tid]*amol_s[tid] : 0.f;
            v = wave_sum(v);
            if (lane == 0) red[w] = v;
        }
        __syncthreads();
        {
            float s1 = 0.f;
#pragma unroll
            for (int i=0;i<8;i++) s1 += red[i];
            if (tid < SEQL)
                mw_s[tid] = leakyf(s1 + s2_s[tid] + mab[0]) + (amk_s[tid]==0.f ? NEGV : 0.f);
        }
        __syncthreads();
        float ev = 0.f;
        if (tid < SEQL) {
            float v = wave_max(mw_s[tid]);
            if (lane == 0) red[8 + w] = v;
        }
        __syncthreads();
        if (tid < SEQL) {
            const float mx = fmaxf(red[8], red[9]);
            ev = expf(mw_s[tid] - mx);
            const float sv = wave_sum(ev);
            if (lane == 0) red[10 + w] = sv;
        }
        __syncthreads();
        if (tid < SEQL) {
            const float inv = 1.f/(red[10] + red[11]);
            const float mv = ev*inv*amk_s[tid];
            mw_s[tid] = mv;
            const float sm = wave_sum(mv);
            if (lane == 0) red[12 + w] = sm;
        }
        __syncthreads();
        const float smw = red[12] + red[13];
        if (c < FPC) {
            float s = 0.f;
            for (int l = half*64; l < half*64 + 64; ++l)
                s = fmaf(mw_s[l], bf2f(acts[l*FPC + c]), s);
            part[half][c][1] = s;
        }
        __syncthreads();
        if (half == 0 && c < FPC) wact_s[c] = part[0][c][1] + part[1][c][1];
        __syncthreads();
        if (c < FPC) {
            float s = 0.f;
            for (int k = half*100; k < half*100 + 100; ++k)
                s = fmaf(wact_s[k], attwT[k*FPC + c], s);
            part[half][c][2] = s;
        }
        __syncthreads();
        if (half == 0 && c < FPC) {
            const float v = part[0][c][2] + part[1][c][2] + smw*attb[c];
            mctx_s[c] = v > 0.f ? v : (expf(v)-1.f);
        }
        __syncthreads();
        if (c < FPC) {
            float g0=0.f,g1=0.f,g2=0.f,g3=0.f,g4=0.f,g5=0.f;
            for (int k = half*100; k < half*100 + 100; ++k){
                const float mc = mctx_s[k], mf = molf_s[k];
                const float* wi = &wihT[k*600];
                const float* wh = &whhT[k*600];
                g0 = fmaf(mc, wi[c],        g0);
                g1 = fmaf(mc, wi[FPC + c],  g1);
                g2 = fmaf(mc, wi[2*FPC + c],g2);
                g3 = fmaf(mf, wh[c],        g3);
                g4 = fmaf(mf, wh[FPC + c],  g4);
                g5 = fmaf(mf, wh[2*FPC + c],g5);
            }
            part[half][c][0]=g0; part[half][c][1]=g1; part[half][c][2]=g2;
            part[half][c][3]=g3; part[half][c][4]=g4; part[half][c][5]=g5;
        }
        __syncthreads();
        float newh = 0.f;
        if (half == 0 && c < FPC) {
            const float gir = part[0][c][0]+part[1][c][0] + bih[c];
            const float giz = part[0][c][1]+part[1][c][1] + bih[FPC+c];
            const float gin = part[0][c][2]+part[1][c][2] + bih[2*FPC+c];
            const float ghr = part[0][c][3]+part[1][c][3] + bhh[c];
            const float ghz = part[0][c][4]+part[1][c][4] + bhh[FPC+c];
            const float ghn = part[0][c][5]+part[1][c][5] + bhh[2*FPC+c];
            const float r = sigm(gir + ghr);
            const float z = sigm(giz + ghz);
            const float n = tanhf(gin + r*ghn);
            newh = (1.f - z)*n + z*molf_s[c];
        }
        __syncthreads();
        if (half == 0 && c < FPC) { molf_s[c] = newh; amol_s[c] = fmaxf(newh, 0.f); }
        __syncthreads();
    }

    {
        float v = (tid < FPC) ? molf_s[tid]*ow[tid] : 0.f;
        v = wave_sum(v);
        if (lane == 0) red[w] = v;
    }
    __syncthreads();
    if (tid == 0) {
        float s = 0.f;
#pragma unroll
        for (int i=0;i<8;i++) s += red[i];
        out[b] = s + ob[0];
    }
}

// ---------------------------------------------------------------------------
extern "C" void kernel_launch(void* const* d_in, const int* in_sizes, int n_in,
                              void* d_out, int out_size, void* d_ws, size_t ws_size,
                              hipStream_t stream)
{
    const float* atom_list = (const float*)d_in[0];
    const float* bond_list = (const float*)d_in[1];
    const int*   adl       = (const int*)d_in[2];
    const int*   bdl       = (const int*)d_in[3];
    const float* amask     = (const float*)d_in[4];
    const float* atom_fc_w = (const float*)d_in[5];
    const float* atom_fc_b = (const float*)d_in[6];
    const float* nb_fc_w   = (const float*)d_in[7];
    const float* nb_fc_b   = (const float*)d_in[8];
    const float* align_w   = (const float*)d_in[9];
    const float* align_b   = (const float*)d_in[10];
    const float* attend_w  = (const float*)d_in[11];
    const float* attend_b  = (const float*)d_in[12];
    const float* gru_wih   = (const float*)d_in[13];
    const float* gru_whh   = (const float*)d_in[14];
    const float* gru_bih   = (const float*)d_in[15];
    const float* gru_bhh   = (const float*)d_in[16];
    const float* mol_align_w  = (const float*)d_in[17];
    const float* mol_align_b  = (const float*)d_in[18];
    const float* mol_attend_w = (const float*)d_in[19];
    const float* mol_attend_b = (const float*)d_in[20];
    const float* mol_gru_wih  = (const float*)d_in[21];
    const float* mol_gru_whh  = (const float*)d_in[22];
    const float* mol_gru_bih  = (const float*)d_in[23];
    const float* mol_gru_bhh  = (const float*)d_in[24];
    const float* output_w  = (const float*)d_in[25];
    const float* output_b  = (const float*)d_in[26];

    float* ws   = (float*)d_ws;
    float* s_aw  = ws;                  // [32768]
    float* attwT = s_aw  + 32768;       // 40000
    float* wihT  = attwT + 40000;       // 120000
    float* whhT  = wihT  + 120000;      // 120000
    float* bpIh  = whhT  + 120000;      // 2304
    float* bpHh  = bpIh  + 2304;        // 2304
    float* wend  = bpHh  + 2304;

    unsigned short* hhA  = (unsigned short*)wend;   // [32768,200] bf16
    unsigned short* hhB  = hhA  + 6553600;
    unsigned short* wnbh = hhB  + 6553600;
    unsigned short* ctxh = wnbh + 6553600;
    unsigned short* aTh  = ctxh + 6553600;          // [32768,200] bf16
    unsigned short* bTh  = aTh  + 6553600;
    unsigned short* w_att = bTh + 6553600;          // 3*200*200
    unsigned short* wpIh  = w_att + 120000;         // 3*768*200
    unsigned short* wpHh  = wpIh + 460800;

    float* outF = (float*)d_out;                    // [32768,200] f32 h (d=2)
    float* outM = outF + (size_t)BL*FPC;            // [256] mol prediction

    const dim3 blk(256);

    // weight prep
    conv_bf<<<(120000+255)/256, blk, 0, stream>>>(attend_w, w_att, 120000);
    conv_perm<<<(3*768*FPC+255)/256, blk, 0, stream>>>(
        gru_wih, gru_whh, gru_bih, gru_bhh, wpIh, wpHh, bpIh, bpHh);
    mol_prep<<<(280000+255)/256, blk, 0, stream>>>(
        mol_attend_w, mol_gru_wih, mol_gru_whh, attwT, wihT, whhT);

    // atom_feature (bf16); aTh = atom@Wa^T (bf16); bTh = bond@Wb^T + b (bf16)
    gemm_bt<1,true,false,true><<<dim3(512,4), blk, 0, stream>>>(
        atom_list, 39, atom_fc_w, 39, atom_fc_b, nullptr, hhA, FPC, BL, FPC, 39);
    gemm_bt<0,false,false,true><<<dim3(512,4), blk, 0, stream>>>(
        atom_list, 39, nb_fc_w, 49, nullptr, nullptr, aTh, FPC, BL, FPC, 39);
    gemm_bt<0,true,false,true><<<dim3(512,4), blk, 0, stream>>>(
        bond_list, 10, nb_fc_w + 39, 49, nb_fc_b, nullptr, bTh, FPC, BL, FPC, 10);

    const unsigned short* hhCur = hhA;
    for (int d=0; d<3; d++) {
        if (d==0)
            attn_radius<true,false><<<BL/4, blk, 0, stream>>>(
                hhA, nullptr, aTh, bTh, adl, bdl, align_w, align_b, wnbh, s_aw);
        else
            attn_radius<false,true><<<BL/4, blk, 0, stream>>>(
                hhCur, hhCur, nullptr, nullptr, adl, nullptr,
                align_w + d*2*FPC, align_b + d, wnbh, s_aw);
        gemm_mfma<2,true><<<dim3(512,2), blk, 0, stream>>>(
            wnbh, FPC, w_att + d*FPC*FPC, FPC, attend_b + d*FPC, s_aw,
            ctxh, FPC, BL, FPC, FPC);
        unsigned short* hhNext = (d==0) ? hhB : ((d==1) ? hhA : nullptr);
        gru_fused<<<dim3(512), blk, 0, stream>>>(
            ctxh, hhCur, wpIh + d*768*FPC, wpHh + d*768*FPC,
            bpIh + d*768, bpHh + d*768,
            hhNext, (d==2) ? outF : nullptr);
        hhCur = (d==0) ? hhB : hhA;
    }

    // molecule phase reads the f32 h written to d_out
    mol_fused<<<BATCH, 512, 0, stream>>>(
        outF, amask, mol_align_w, mol_align_b, attwT, mol_attend_b,
        wihT, whhT, mol_gru_bih, mol_gru_bhh, output_w, output_b, outM);
}